// Round 8
// baseline (175.414 us; speedup 1.0000x reference)
//
#include <hip/hip_runtime.h>
#include <math.h>

// OnlineTripletLoss on MI355X — Round 18.
// R16/R17 both died with identical harness errors (Trio nursery) — repeated identical
// failure for identical source implicates the kernel. Audit cleared the triangular
// mapping (terminates), co-residency (137KB/2 blocks), K-loop WAR. The only novel
// sync construct vs all passing rounds was the DUAL panel-counter spin (off-diag
// blocks wait on 2 counters). R18 replaces it with a single grid-wide counter
// barrier (1 atomicAdd + 1 spin; provably safe at 512 co-resident blocks, proven
// by R10/R12). Symmetry design kept: lower-triangle 128x128 tiles, 496 off-diag
// (row+col contributions) + 16 diag = 512 blocks = 2/CU. GEMM+staging -47%.
// ws: sq[N] | hp[N] | hn_fall[N] | hn_semi[N] | bars[2048] | pan[N*2D] f16

constexpr float MARGIN = 0.3f;

typedef _Float16 half8    __attribute__((ext_vector_type(8)));
typedef float    floatx16 __attribute__((ext_vector_type(16)));

#define GLD_LDS16(gp, lp)                                                              \
    __builtin_amdgcn_global_load_lds(                                                  \
        (const __attribute__((address_space(1))) void*)(gp),                           \
        (__attribute__((address_space(3))) void*)(lp), 16, 0, 0)

// prep: 8 rows/block (512 blocks); builds pan[p][kc][r][8] (kc<64 hi, kc>=64 lo),
// sq, per-row init, bars.
__global__ __launch_bounds__(256)
void prep_kernel(const float* __restrict__ e, _Float16* __restrict__ pan,
                 float* __restrict__ sq, unsigned int* __restrict__ hp,
                 unsigned int* __restrict__ hn_fall, unsigned int* __restrict__ hn_semi,
                 unsigned int* __restrict__ bars, int N, int D) {
    __shared__ float red[256];
    if (blockIdx.x == 0) {
        if (threadIdx.x == 0) bars[0] = 0u;          // grid barrier counter
        else if (threadIdx.x == 1) bars[1984] = 0u;  // done counter
    }
    const int r0  = blockIdx.x * 8;
    const int p   = r0 >> 7;
    const int rl  = r0 & 127;
    const int r   = threadIdx.x & 7;
    const int c8  = threadIdx.x >> 3;
    const int row = r0 + r;
    const float* er = e + (size_t)row * D;
    float s = 0.f;
    #pragma unroll
    for (int it = 0; it < 2; ++it) {
        const int kw = c8 + it * 32;
        const float4 x0 = *(const float4*)&er[kw * 8];
        const float4 x1 = *(const float4*)&er[kw * 8 + 4];
        const float xv[8] = {x0.x, x0.y, x0.z, x0.w, x1.x, x1.y, x1.z, x1.w};
        half8 hi, lo;
        #pragma unroll
        for (int jj = 0; jj < 8; ++jj) {
            _Float16 h = (_Float16)xv[jj];
            hi[jj] = h;
            lo[jj] = (_Float16)(xv[jj] - (float)h);
            s += xv[jj] * xv[jj];
        }
        *(half8*)&pan[((size_t)(p * 128 + kw) * 128 + rl + r) * 8]      = hi;
        *(half8*)&pan[((size_t)(p * 128 + 64 + kw) * 128 + rl + r) * 8] = lo;
    }
    red[threadIdx.x] = s;
    __syncthreads();
    if (threadIdx.x < 8) {
        float t = 0.f;
        #pragma unroll
        for (int c = 0; c < 32; ++c) t += red[threadIdx.x + 8 * c];
        const int rw = r0 + threadIdx.x;
        sq[rw]      = t;
        hp[rw]      = 0u;
        hn_fall[rw] = 0u;
        hn_semi[rw] = 0x7f800000u;
    }
}

// Fused: triangular 128x128 tiles. 256 thr = 4 waves (2x2) of 64x64.
// Buffer (16384 halves = 32 KB): A[kcl 0..7][128][8] | B[kcl 0..7][128][8] @8192.
// kcl 0..3 = hi k-chunks (4t..4t+3), 4..7 = lo. Double-buffered. 2 blocks/CU.
__global__ __launch_bounds__(256, 2)
void fused_kernel(const _Float16* __restrict__ pan, const int* __restrict__ labels,
                  const float* __restrict__ sq,
                  unsigned int* __restrict__ hp,
                  unsigned int* __restrict__ hn_fall,
                  unsigned int* __restrict__ hn_semi,
                  unsigned int* __restrict__ bars,
                  float* __restrict__ out,
                  int N, int D, unsigned int nblocks) {
    __shared__ __attribute__((aligned(16))) _Float16 S[2][16384];   // 64 KB
    __shared__ float sq_r[128], sq_c[128], hp_r[128], hp_c[128];
    __shared__ int   lab_r[128], lab_c[128];
    __shared__ int   lastflag;

    const int tid  = threadIdx.x;
    const int lane = tid & 63;
    const int wave = tid >> 6;             // 0..3
    const int wr   = (wave >> 1) * 64;     // 0,64
    const int wcol = (wave & 1) * 64;      // 0,64
    const int mrow = lane & 31;
    const int half_id = lane >> 5;

    // triangular mapping: b<16 -> diag (py=px=b); else off-diag py<px
    int py, px;
    if (blockIdx.x < 16) {
        py = px = blockIdx.x;
    } else {
        int rem = blockIdx.x - 16, q = 0;
        while (rem >= 31 - q) { rem -= 31 - q; ++q; }
        py = q; px = q + 1 + rem;
    }
    const bool diag = (py == px);
    const int rowBase = py * 128;
    const int colBase = px * 128;

    if (tid < 128) {
        sq_r[tid]  = sq[rowBase + tid];
        lab_r[tid] = labels[rowBase + tid];
    } else {
        const int t2 = tid - 128;
        sq_c[t2]  = sq[colBase + t2];
        lab_c[t2] = labels[colBase + t2];
    }

    floatx16 acc[2][2];   // acc[bj][ai]: cols in regs (bj), rows in lanes (ai)
    #pragma unroll
    for (int b = 0; b < 2; ++b)
        #pragma unroll
        for (int a = 0; a < 2; ++a)
            #pragma unroll
            for (int r = 0; r < 16; ++r) acc[b][a][r] = 0.f;

    // 32 slabs of 1 KB per K-tile: A = 8 kcl x 2 row-halves, B same @ +8192.
    // wave w owns slabs 8w..8w+7.
    auto stage_slab = [&](int buf, int t, int u) {
        const int s = wave * 8 + u;        // 0..31
        int kcl, pp, rowin, lofs;
        if (s < 16) {                      // A slab
            kcl = s >> 1; const int rh = s & 1;
            pp    = py;
            rowin = rh * 64 + lane;
            lofs  = (kcl * 128 + rh * 64) * 8;
        } else {                           // B slab
            const int u2 = s - 16;
            kcl = u2 >> 1; const int ch = u2 & 1;
            pp    = px;
            rowin = ch * 64 + lane;
            lofs  = 8192 + (kcl * 128 + ch * 64) * 8;
        }
        const int kc = (kcl < 4) ? (4 * t + kcl) : (64 + 4 * t + (kcl - 4));
        const _Float16* g = pan + ((size_t)(pp * 128 + kc) * 128 + rowin) * 8;
        GLD_LDS16(g, &S[buf][lofs]);
    };

    // prologue: stage K-tile 0, full drain once (also covers meta-LDS writes).
    #pragma unroll
    for (int u = 0; u < 8; ++u) stage_slab(0, 0, u);
    __syncthreads();

    #pragma unroll 1
    for (int t = 0; t < 16; ++t) {
        const int cur = t & 1;
        const _Float16* Sc = &S[cur][0];
        if (t + 1 < 16) {
            #pragma unroll
            for (int u = 0; u < 8; ++u) stage_slab(cur ^ 1, t + 1, u);
        }
        auto mm = [&](const half8* bq, const half8* aq) {
            #pragma unroll
            for (int bj = 0; bj < 2; ++bj)
                #pragma unroll
                for (int ai = 0; ai < 2; ++ai)
                    acc[bj][ai] = __builtin_amdgcn_mfma_f32_32x32x16_f16(
                        bq[bj], aq[ai], acc[bj][ai], 0, 0, 0);
        };
        #pragma unroll
        for (int ks = 0; ks < 2; ++ks) {
            const int kb = 2 * ks;
            half8 ah[2], bh[2], al[2], bl[2];
            #pragma unroll
            for (int ai = 0; ai < 2; ++ai)
                ah[ai] = *(const half8*)&Sc[((kb + half_id) * 128 + wr + ai * 32 + mrow) * 8];
            #pragma unroll
            for (int bj = 0; bj < 2; ++bj)
                bh[bj] = *(const half8*)&Sc[8192 + ((kb + half_id) * 128 + wcol + bj * 32 + mrow) * 8];
            #pragma unroll
            for (int ai = 0; ai < 2; ++ai)
                al[ai] = *(const half8*)&Sc[((4 + kb + half_id) * 128 + wr + ai * 32 + mrow) * 8];
            #pragma unroll
            for (int bj = 0; bj < 2; ++bj)
                bl[bj] = *(const half8*)&Sc[8192 + ((4 + kb + half_id) * 128 + wcol + bj * 32 + mrow) * 8];
            __builtin_amdgcn_s_setprio(1);
            mm(bh, ah);                    // hi.hi
            mm(bh, al);                    // lo.hi
            mm(bl, ah);                    // hi.lo
            __builtin_amdgcn_s_setprio(0);
        }
        asm volatile("s_waitcnt vmcnt(0)" ::: "memory");
        __builtin_amdgcn_s_barrier();
        asm volatile("" ::: "memory");
    }

    // ---- epilogue. rows in lanes: row(ai) = wr + ai*32 + mrow ----
    float sqr[2]; int labr[2];
    #pragma unroll
    for (int ai = 0; ai < 2; ++ai) {
        sqr[ai]  = sq_r[wr + ai * 32 + mrow];
        labr[ai] = lab_r[wr + ai * 32 + mrow];
    }

    // ---- phase 1 row: hp / hn_fall for rows of panel py ----
    #pragma unroll
    for (int ai = 0; ai < 2; ++ai) {
        float vp = 0.f, vn = 0.f;
        #pragma unroll
        for (int bj = 0; bj < 2; ++bj) {
            #pragma unroll
            for (int r = 0; r < 16; ++r) {
                const int c = wcol + bj * 32 + (r & 3) + 8 * (r >> 2) + 4 * half_id;
                float d = sqrtf(fmaxf(sqr[ai] + sq_c[c] - 2.0f * acc[bj][ai][r], 1e-12f));
                const bool pos = (labr[ai] == lab_c[c]);
                vp = fmaxf(vp, pos ? d : 0.f);
                vn = fmaxf(vn, pos ? 0.f : d);
            }
        }
        vp = fmaxf(vp, __shfl_xor(vp, 32, 64));   // merge col halves
        vn = fmaxf(vn, __shfl_xor(vn, 32, 64));
        if (half_id == 0) {
            atomicMax(&hp[rowBase + wr + ai * 32 + mrow],      __float_as_uint(vp));
            atomicMax(&hn_fall[rowBase + wr + ai * 32 + mrow], __float_as_uint(vn));
        }
    }

    // ---- phase 1 col (off-diag only): same distances, anchors = cols (panel px).
    // reduce over rows: in-reg over ai, butterfly over 32 mrow lanes.
    if (!diag) {
        #pragma unroll
        for (int bj = 0; bj < 2; ++bj) {
            #pragma unroll
            for (int r = 0; r < 16; ++r) {
                const int c = wcol + bj * 32 + (r & 3) + 8 * (r >> 2) + 4 * half_id;
                const float sc = sq_c[c]; const int lc = lab_c[c];
                float vp = 0.f, vn = 0.f;
                #pragma unroll
                for (int ai = 0; ai < 2; ++ai) {
                    float d = sqrtf(fmaxf(sqr[ai] + sc - 2.0f * acc[bj][ai][r], 1e-12f));
                    const bool pos = (labr[ai] == lc);
                    vp = fmaxf(vp, pos ? d : 0.f);
                    vn = fmaxf(vn, pos ? 0.f : d);
                }
                #pragma unroll
                for (int off = 16; off; off >>= 1) {
                    vp = fmaxf(vp, __shfl_xor(vp, off, 64));
                    vn = fmaxf(vn, __shfl_xor(vn, off, 64));
                }
                if (mrow == 0) {
                    atomicMax(&hp[colBase + c],      __float_as_uint(vp));
                    atomicMax(&hn_fall[colBase + c], __float_as_uint(vn));
                }
            }
        }
    }

    // ---- grid-wide barrier: single counter; all 512 blocks co-resident ----
    __syncthreads();
    if (tid == 0) {
        __threadfence();
        atomicAdd(&bars[0], 1u);
        while (__hip_atomic_load(&bars[0], __ATOMIC_ACQUIRE,
                                 __HIP_MEMORY_SCOPE_AGENT) < nblocks)
            __builtin_amdgcn_s_sleep(32);
    }
    __syncthreads();
    if (tid < 128)
        hp_r[tid] = __uint_as_float(__hip_atomic_load(&hp[rowBase + tid],
                                    __ATOMIC_RELAXED, __HIP_MEMORY_SCOPE_AGENT));
    else
        hp_c[tid - 128] = __uint_as_float(__hip_atomic_load(&hp[colBase + tid - 128],
                                          __ATOMIC_RELAXED, __HIP_MEMORY_SCOPE_AGENT));
    __syncthreads();

    // ---- phase 2 row: hn_semi = min{d : neg, d > hp(row)} ----
    #pragma unroll
    for (int ai = 0; ai < 2; ++ai) {
        const float hpv = hp_r[wr + ai * 32 + mrow];
        float vm = __builtin_inff();
        #pragma unroll
        for (int bj = 0; bj < 2; ++bj) {
            #pragma unroll
            for (int r = 0; r < 16; ++r) {
                const int c = wcol + bj * 32 + (r & 3) + 8 * (r >> 2) + 4 * half_id;
                float d = sqrtf(fmaxf(sqr[ai] + sq_c[c] - 2.0f * acc[bj][ai][r], 1e-12f));
                const bool cand = (labr[ai] != lab_c[c]) && (d > hpv);
                vm = fminf(vm, cand ? d : __builtin_inff());
            }
        }
        vm = fminf(vm, __shfl_xor(vm, 32, 64));
        if (half_id == 0)
            atomicMin(&hn_semi[rowBase + wr + ai * 32 + mrow], __float_as_uint(vm));
    }

    // ---- phase 2 col (off-diag only) ----
    if (!diag) {
        #pragma unroll
        for (int bj = 0; bj < 2; ++bj) {
            #pragma unroll
            for (int r = 0; r < 16; ++r) {
                const int c = wcol + bj * 32 + (r & 3) + 8 * (r >> 2) + 4 * half_id;
                const float sc = sq_c[c]; const int lc = lab_c[c];
                const float hpv = hp_c[c];
                float vm = __builtin_inff();
                #pragma unroll
                for (int ai = 0; ai < 2; ++ai) {
                    float d = sqrtf(fmaxf(sqr[ai] + sc - 2.0f * acc[bj][ai][r], 1e-12f));
                    const bool cand = (labr[ai] != lc) && (d > hpv);
                    vm = fminf(vm, cand ? d : __builtin_inff());
                }
                #pragma unroll
                for (int off = 16; off; off >>= 1)
                    vm = fminf(vm, __shfl_xor(vm, off, 64));
                if (mrow == 0)
                    atomicMin(&hn_semi[colBase + c], __float_as_uint(vm));
            }
        }
    }

    // ---- last-block final reduction ----
    __syncthreads();
    if (tid == 0) {
        __threadfence();
        unsigned int old = atomicAdd(&bars[1984], 1u);
        lastflag = (old == nblocks - 1) ? 1 : 0;
    }
    __syncthreads();
    if (!lastflag) return;
    if (tid == 0) __threadfence();      // acquire before cross-XCD reads
    __syncthreads();

    float* FS = (float*)&S[0][0];       // 256 sums
    int*   IC = (int*)(FS + 256);       // 256 counts
    int*   IA = IC + 256;               // 256 any-flags
    int any = 0;
    for (int r = tid; r < N; r += 256) {
        float h  = __uint_as_float(__hip_atomic_load(&hp[r],      __ATOMIC_RELAXED, __HIP_MEMORY_SCOPE_AGENT));
        float hs = __uint_as_float(__hip_atomic_load(&hn_semi[r], __ATOMIC_RELAXED, __HIP_MEMORY_SCOPE_AGENT));
        any |= (hs < h + MARGIN) ? 1 : 0;
    }
    IA[tid] = any;
    __syncthreads();
    for (int s = 128; s; s >>= 1) {
        if (tid < s) IA[tid] |= IA[tid + s];
        __syncthreads();
    }
    const bool has_semi = IA[0] != 0;
    float sum = 0.f; int valid = 0;
    for (int r = tid; r < N; r += 256) {
        float h  = __uint_as_float(__hip_atomic_load(&hp[r], __ATOMIC_RELAXED, __HIP_MEMORY_SCOPE_AGENT));
        float hn = has_semi
            ? __uint_as_float(__hip_atomic_load(&hn_semi[r], __ATOMIC_RELAXED, __HIP_MEMORY_SCOPE_AGENT))
            : __uint_as_float(__hip_atomic_load(&hn_fall[r], __ATOMIC_RELAXED, __HIP_MEMORY_SCOPE_AGENT));
        float t = fmaxf(h - hn + MARGIN, 0.f);
        if (!(t > 0.f)) t = 0.f;        // -inf guard (hn=+inf rows)
        sum += t;
        valid += (t > 0.f) ? 1 : 0;
    }
    FS[tid] = sum; IC[tid] = valid;
    __syncthreads();
    for (int s = 128; s; s >>= 1) {
        if (tid < s) { FS[tid] += FS[tid + s]; IC[tid] += IC[tid + s]; }
        __syncthreads();
    }
    if (tid == 0) {
        float total = FS[0]; int v = IC[0];
        out[0] = (v > 0) ? (total / (float)v) : (total / (float)N);
    }
}

extern "C" void kernel_launch(void* const* d_in, const int* in_sizes, int n_in,
                              void* d_out, int out_size, void* d_ws, size_t ws_size,
                              hipStream_t stream) {
    const float* e      = (const float*)d_in[0];
    const int*   labels = (const int*)d_in[1];
    const int N = in_sizes[1];
    const int D = in_sizes[0] / N;
    float* out = (float*)d_out;

    float*        sq      = (float*)d_ws;
    unsigned int* hp      = (unsigned int*)d_ws + N;
    unsigned int* hn_fall = hp + N;
    unsigned int* hn_semi = hn_fall + N;
    unsigned int* bars    = hn_semi + N;     // bars[0] = grid barrier, bars[1984] = done

    const size_t small_bytes = ((size_t)(4 * N + 2048) * 4 + 255) & ~(size_t)255;
    _Float16* pan = (_Float16*)((char*)d_ws + small_bytes);

    prep_kernel<<<N / 8, 256, 0, stream>>>(e, pan, sq, hp, hn_fall, hn_semi, bars, N, D);

    // triangular grid: 16 diag + 496 off-diag = 512 blocks = 2/CU co-resident
    fused_kernel<<<512, 256, 0, stream>>>(pan, labels, sq, hp, hn_fall, hn_semi,
                                          bars, out, N, D, 512u);
}

// Round 10
// 151.819 us; speedup vs baseline: 1.1554x; 1.1554x over previous
//
#include <hip/hip_runtime.h>
#include <math.h>

// OnlineTripletLoss on MI355X — Round 20 (= R19 resubmit; R19 died with the same
// acquire-side infra error as R11 ("container failed twice"), which R12 proved was
// a flake by passing the identical source. Audit re-cleared R19: 1 block/CU x 256
// blocks co-resident for the grid barrier; release/acquire pattern identical to the
// hp-readback used in all passing rounds; hipMemsetAsync is graph-capturable.)
// Session model: fused == 82-85us across 3 structures; total == 137-142 -> fixed
//   ~55us outside fused = prep exec + 2nd launch + harness resets. R19/R20 fuse
//   everything into ONE kernel: prep-phase (16 rows/block) -> threadfence -> grid
//   counter barrier -> R15's verbatim 256x256 K-loop + epilogue.
// ws: sq[N] | hp[N] | hn_fall[N] | hn_semi[N] | bars[2048] | pan[N*2D] f16

constexpr float MARGIN = 0.3f;

typedef _Float16 half8    __attribute__((ext_vector_type(8)));
typedef float    floatx16 __attribute__((ext_vector_type(16)));

#define GLD_LDS16(gp, lp)                                                              \
    __builtin_amdgcn_global_load_lds(                                                  \
        (const __attribute__((address_space(1))) void*)(gp),                           \
        (__attribute__((address_space(3))) void*)(lp), 16, 0, 0)

// Single fused kernel: 256 blocks x 512 thr, 1 block/CU (~135 KB LDS), all resident.
// Phase P (prep): 16 rows/block -> pan (hi/lo f16 split), sq, hp/hn init.
// Grid barrier. Then tile 256x256 GEMM-epilogue exactly as R15.
__global__ __launch_bounds__(512, 1)
void fused_kernel(const float* __restrict__ e, const int* __restrict__ labels,
                  _Float16* __restrict__ pan, float* __restrict__ sq,
                  unsigned int* __restrict__ hp,
                  unsigned int* __restrict__ hn_fall,
                  unsigned int* __restrict__ hn_semi,
                  unsigned int* __restrict__ bars,
                  float* __restrict__ out,
                  int N, int D, unsigned int nrowblocks, unsigned int nblocks) {
    __shared__ __attribute__((aligned(16))) _Float16 S[2][32768];   // 128 KB
    __shared__ float red[512];
    __shared__ float sq_r[256], sq_c[256], hp_r[256];
    __shared__ int   lab_r[256], lab_c[256];
    __shared__ int   lastflag;

    const int tid  = threadIdx.x;

    // ================= phase P: prep (16 rows/block) =================
    {
        const int r0  = blockIdx.x * 16;       // 256 blocks * 16 = 4096 rows
        const int p   = r0 >> 7;
        const int rl  = r0 & 127;
        const int rr  = tid & 15;
        const int c8  = tid >> 4;              // 0..31
        const int row = r0 + rr;
        const float* er = e + (size_t)row * D;
        float s = 0.f;
        #pragma unroll
        for (int it = 0; it < 2; ++it) {
            const int kw = c8 + it * 32;       // 0..63
            const float4 x0 = *(const float4*)&er[kw * 8];
            const float4 x1 = *(const float4*)&er[kw * 8 + 4];
            const float xv[8] = {x0.x, x0.y, x0.z, x0.w, x1.x, x1.y, x1.z, x1.w};
            half8 hi, lo;
            #pragma unroll
            for (int jj = 0; jj < 8; ++jj) {
                _Float16 h = (_Float16)xv[jj];
                hi[jj] = h;
                lo[jj] = (_Float16)(xv[jj] - (float)h);
                s += xv[jj] * xv[jj];
            }
            *(half8*)&pan[((size_t)(p * 128 + kw) * 128 + rl + rr) * 8]      = hi;
            *(half8*)&pan[((size_t)(p * 128 + 64 + kw) * 128 + rl + rr) * 8] = lo;
        }
        red[tid] = s;
        __syncthreads();
        if (tid < 16) {
            float t = 0.f;
            #pragma unroll
            for (int c = 0; c < 32; ++c) t += red[tid + 16 * c];
            const int rw = r0 + tid;
            sq[rw]      = t;
            hp[rw]      = 0u;           // max identity
            hn_fall[rw] = 0u;
            hn_semi[rw] = 0x7f800000u;  // +inf
        }
    }

    // ---- grid barrier: all 256 blocks (1/CU, co-resident). bars[0] zeroed by
    // the hipMemsetAsync enqueued before this kernel. ----
    __syncthreads();
    if (tid == 0) {
        __threadfence();                 // release pan/sq/init to agent scope
        atomicAdd(&bars[0], 1u);
        while (__hip_atomic_load(&bars[0], __ATOMIC_ACQUIRE,
                                 __HIP_MEMORY_SCOPE_AGENT) < nblocks)
            __builtin_amdgcn_s_sleep(32);
    }
    __syncthreads();

    // ================= phase G: 256x256 tile GEMM (R15 core) =================
    const int lane = tid & 63;
    const int wave = tid >> 6;             // 0..7
    const int wr   = (wave >> 2) * 128;    // 0,128
    const int wcol = (wave & 3) * 64;      // 0,64,128,192
    const int mrow = lane & 31;
    const int half_id = lane >> 5;

    // XCD swizzle: each of 8 XCDs gets a 4(px) x 8(py) region of the 16x16 grid
    const int j  = blockIdx.x & 7;
    const int i  = blockIdx.x >> 3;        // 0..31
    const int px = (j & 3) * 4 + (i & 3);          // 0..15 (256-col tiles)
    const int py = (j >> 2) * 8 + (i >> 2);        // 0..15 (256-row tiles)
    const int rowBase = py * 256;
    const int colBase = px * 256;

    if (tid < 256) {
        sq_r[tid]  = sq[rowBase + tid];
        lab_r[tid] = labels[rowBase + tid];
    } else {
        const int t2 = tid - 256;
        sq_c[t2]  = sq[colBase + t2];
        lab_c[t2] = labels[colBase + t2];
    }

    floatx16 acc[2][4];   // acc[bj][ai]: cols in regs (bj), rows in lanes (ai)
    #pragma unroll
    for (int b = 0; b < 2; ++b)
        #pragma unroll
        for (int a = 0; a < 4; ++a)
            #pragma unroll
            for (int r = 0; r < 16; ++r) acc[b][a][r] = 0.f;

    // 64 slabs of 1 KB per K-tile: A = 8 kcl x 4 row-quarters, B same @ +16384.
    // wave w owns slabs 8w..8w+7.
    auto stage_slab = [&](int buf, int t, int u) {
        const int s = wave * 8 + u;
        int kcl, pp, rowin, lofs;
        if (s < 32) {                      // A slab
            kcl = s >> 2; const int rq = s & 3;
            pp    = 2 * py + (rq >> 1);
            rowin = (rq & 1) * 64 + lane;
            lofs  = (kcl * 256 + rq * 64) * 8;
        } else {                           // B slab
            const int u2 = s - 32;
            kcl = u2 >> 2; const int cq = u2 & 3;
            pp    = 2 * px + (cq >> 1);
            rowin = (cq & 1) * 64 + lane;
            lofs  = 16384 + (kcl * 256 + cq * 64) * 8;
        }
        const int kc = (kcl < 4) ? (4 * t + kcl) : (64 + 4 * t + (kcl - 4));
        const _Float16* g = pan + ((size_t)(pp * 128 + kc) * 128 + rowin) * 8;
        GLD_LDS16(g, &S[buf][lofs]);
    };

    // prologue: stage K-tile 0, full drain once.
    #pragma unroll
    for (int u = 0; u < 8; ++u) stage_slab(0, 0, u);
    __syncthreads();

    #pragma unroll 1
    for (int t = 0; t < 16; ++t) {
        const int cur = t & 1;
        const _Float16* Sc = &S[cur][0];
        if (t + 1 < 16) {
            #pragma unroll
            for (int u = 0; u < 8; ++u) stage_slab(cur ^ 1, t + 1, u);
        }
        auto mm = [&](const half8* bq, const half8* aq) {
            #pragma unroll
            for (int bj = 0; bj < 2; ++bj)
                #pragma unroll
                for (int ai = 0; ai < 4; ++ai)
                    acc[bj][ai] = __builtin_amdgcn_mfma_f32_32x32x16_f16(
                        bq[bj], aq[ai], acc[bj][ai], 0, 0, 0);
        };
        #pragma unroll
        for (int ks = 0; ks < 2; ++ks) {
            const int kb = 2 * ks;
            half8 ah[4], bh[2], al[4], bl[2];
            #pragma unroll
            for (int ai = 0; ai < 4; ++ai)
                ah[ai] = *(const half8*)&Sc[((kb + half_id) * 256 + wr + ai * 32 + mrow) * 8];
            #pragma unroll
            for (int bj = 0; bj < 2; ++bj)
                bh[bj] = *(const half8*)&Sc[16384 + ((kb + half_id) * 256 + wcol + bj * 32 + mrow) * 8];
            #pragma unroll
            for (int ai = 0; ai < 4; ++ai)
                al[ai] = *(const half8*)&Sc[((4 + kb + half_id) * 256 + wr + ai * 32 + mrow) * 8];
            #pragma unroll
            for (int bj = 0; bj < 2; ++bj)
                bl[bj] = *(const half8*)&Sc[16384 + ((4 + kb + half_id) * 256 + wcol + bj * 32 + mrow) * 8];
            __builtin_amdgcn_s_setprio(1);
            mm(bh, ah);                    // hi.hi
            mm(bh, al);                    // lo.hi
            mm(bl, ah);                    // hi.lo
            __builtin_amdgcn_s_setprio(0);
        }
        asm volatile("s_waitcnt vmcnt(0)" ::: "memory");
        __builtin_amdgcn_s_barrier();
        asm volatile("" ::: "memory");
    }

    // ---- epilogue: rows in lanes. row(ai) = wr + ai*32 + mrow ----
    float sqr[4]; int labr[4];
    #pragma unroll
    for (int ai = 0; ai < 4; ++ai) {
        sqr[ai]  = sq_r[wr + ai * 32 + mrow];
        labr[ai] = lab_r[wr + ai * 32 + mrow];
    }

    // ---- phase 1: hp / hn_fall ----
    #pragma unroll
    for (int ai = 0; ai < 4; ++ai) {
        float vp = 0.f, vn = 0.f;
        #pragma unroll
        for (int bj = 0; bj < 2; ++bj) {
            #pragma unroll
            for (int r = 0; r < 16; ++r) {
                const int c = wcol + bj * 32 + (r & 3) + 8 * (r >> 2) + 4 * half_id;
                float d = sqrtf(fmaxf(sqr[ai] + sq_c[c] - 2.0f * acc[bj][ai][r], 1e-12f));
                const bool pos = (labr[ai] == lab_c[c]);
                vp = fmaxf(vp, pos ? d : 0.f);
                vn = fmaxf(vn, pos ? 0.f : d);
            }
        }
        vp = fmaxf(vp, __shfl_xor(vp, 32, 64));   // merge col halves
        vn = fmaxf(vn, __shfl_xor(vn, 32, 64));
        if (half_id == 0) {
            atomicMax(&hp[rowBase + wr + ai * 32 + mrow],      __float_as_uint(vp));
            atomicMax(&hn_fall[rowBase + wr + ai * 32 + mrow], __float_as_uint(vn));
        }
    }

    // ---- per-row-panel barrier: 16 col-blocks share each py; all co-resident ----
    __syncthreads();
    unsigned int* ctr = &bars[32 + py * 32];
    if (tid == 0) {
        __threadfence();
        atomicAdd(ctr, 1u);
        while (__hip_atomic_load(ctr, __ATOMIC_ACQUIRE, __HIP_MEMORY_SCOPE_AGENT)
               < nrowblocks)
            __builtin_amdgcn_s_sleep(32);
    }
    __syncthreads();
    if (tid < 256)
        hp_r[tid] = __uint_as_float(__hip_atomic_load(&hp[rowBase + tid],
                                    __ATOMIC_RELAXED, __HIP_MEMORY_SCOPE_AGENT));
    __syncthreads();

    // ---- phase 2: hn_semi = min{d : neg, d > hp} ----
    #pragma unroll
    for (int ai = 0; ai < 4; ++ai) {
        const float hpv = hp_r[wr + ai * 32 + mrow];
        float vm = __builtin_inff();
        #pragma unroll
        for (int bj = 0; bj < 2; ++bj) {
            #pragma unroll
            for (int r = 0; r < 16; ++r) {
                const int c = wcol + bj * 32 + (r & 3) + 8 * (r >> 2) + 4 * half_id;
                float d = sqrtf(fmaxf(sqr[ai] + sq_c[c] - 2.0f * acc[bj][ai][r], 1e-12f));
                const bool cand = (labr[ai] != lab_c[c]) && (d > hpv);
                vm = fminf(vm, cand ? d : __builtin_inff());
            }
        }
        vm = fminf(vm, __shfl_xor(vm, 32, 64));
        if (half_id == 0)
            atomicMin(&hn_semi[rowBase + wr + ai * 32 + mrow], __float_as_uint(vm));
    }

    // ---- last-block final reduction ----
    __syncthreads();
    if (tid == 0) {
        __threadfence();
        unsigned int old = atomicAdd(&bars[992], 1u);
        lastflag = (old == nblocks - 1) ? 1 : 0;
    }
    __syncthreads();
    if (!lastflag) return;
    if (tid == 0) __threadfence();      // acquire before cross-XCD reads
    __syncthreads();

    float* FS = (float*)&S[0][0];       // 512 sums
    int*   IC = (int*)(FS + 512);       // 512 counts
    int*   IA = IC + 512;               // 512 any-flags
    int any = 0;
    for (int r = tid; r < N; r += 512) {
        float h  = __uint_as_float(__hip_atomic_load(&hp[r],      __ATOMIC_RELAXED, __HIP_MEMORY_SCOPE_AGENT));
        float hs = __uint_as_float(__hip_atomic_load(&hn_semi[r], __ATOMIC_RELAXED, __HIP_MEMORY_SCOPE_AGENT));
        any |= (hs < h + MARGIN) ? 1 : 0;
    }
    IA[tid] = any;
    __syncthreads();
    for (int s = 256; s; s >>= 1) {
        if (tid < s) IA[tid] |= IA[tid + s];
        __syncthreads();
    }
    const bool has_semi = IA[0] != 0;
    float sum = 0.f; int valid = 0;
    for (int r = tid; r < N; r += 512) {
        float h  = __uint_as_float(__hip_atomic_load(&hp[r], __ATOMIC_RELAXED, __HIP_MEMORY_SCOPE_AGENT));
        float hn = has_semi
            ? __uint_as_float(__hip_atomic_load(&hn_semi[r], __ATOMIC_RELAXED, __HIP_MEMORY_SCOPE_AGENT))
            : __uint_as_float(__hip_atomic_load(&hn_fall[r], __ATOMIC_RELAXED, __HIP_MEMORY_SCOPE_AGENT));
        float t = fmaxf(h - hn + MARGIN, 0.f);
        if (!(t > 0.f)) t = 0.f;        // -inf guard (hn=+inf rows)
        sum += t;
        valid += (t > 0.f) ? 1 : 0;
    }
    FS[tid] = sum; IC[tid] = valid;
    __syncthreads();
    for (int s = 256; s; s >>= 1) {
        if (tid < s) { FS[tid] += FS[tid + s]; IC[tid] += IC[tid + s]; }
        __syncthreads();
    }
    if (tid == 0) {
        float total = FS[0]; int v = IC[0];
        out[0] = (v > 0) ? (total / (float)v) : (total / (float)N);
    }
}

extern "C" void kernel_launch(void* const* d_in, const int* in_sizes, int n_in,
                              void* d_out, int out_size, void* d_ws, size_t ws_size,
                              hipStream_t stream) {
    const float* e      = (const float*)d_in[0];
    const int*   labels = (const int*)d_in[1];
    const int N = in_sizes[1];
    const int D = in_sizes[0] / N;
    float* out = (float*)d_out;

    float*        sq      = (float*)d_ws;
    unsigned int* hp      = (unsigned int*)d_ws + N;
    unsigned int* hn_fall = hp + N;
    unsigned int* hn_semi = hn_fall + N;
    unsigned int* bars    = hn_semi + N;     // [0]=grid, [32+32p]=panel, [992]=done

    const size_t small_bytes = ((size_t)(4 * N + 2048) * 4 + 255) & ~(size_t)255;
    _Float16* pan = (_Float16*)((char*)d_ws + small_bytes);

    hipMemsetAsync(bars, 0, 2048 * sizeof(unsigned int), stream);

    const int ntx = N / 256, nty = N / 256;  // 16 x 16 tiles = 256 blocks = 1/CU
    fused_kernel<<<ntx * nty, 512, 0, stream>>>(e, labels, pan, sq, hp, hn_fall,
                                                hn_semi, bars, out, N, D,
                                                (unsigned)ntx, (unsigned)(ntx * nty));
}

// Round 11
// 128.747 us; speedup vs baseline: 1.3625x; 1.1792x over previous
//
#include <hip/hip_runtime.h>
#include <math.h>

// OnlineTripletLoss on MI355X — Round 21 (final polish).
// R20 post-mortem: single-kernel fusion hit its predicted dispatch time (100us =
//   prep 15 + GEMM 85) but TOTAL rose to 151.8 -> the ~50us non-kernel time is
//   harness-fixed (reset dispatch train), and in-kernel prep (1 blk/CU behind a
//   grid barrier) is slower than the 512-block prep kernel. Reverted to two-kernel.
// Corrected accounting: GEMM = 51.5 GFLOP (2*N^2*D x 3 passes); 82-85us fused
//   == ~650-690 TF == ~75% of the m97-structure class at K=512 — near the known
//   structure ceiling; 3 re-schedules landed identical.
// R21 = R15 (best timed total, 137.5) + d^2-domain epilogue: sqrt is monotone, so
//   hp/hn_fall = max d^2, semi-hard filter d^2 > hp^2, hn_semi = min d^2 — removes
//   256 v_sqrt + clamps per thread from both passes; final 4096-row reduction does
//   the sqrts. Bit-safe for uint atomics (all values >= 0).
// ws: sq[N] | hp[N] | hn_fall[N] | hn_semi[N] | bars[1024] | pad | pan[N*2D] f16

constexpr float MARGIN = 0.3f;

typedef _Float16 half8    __attribute__((ext_vector_type(8)));
typedef float    floatx16 __attribute__((ext_vector_type(16)));

#define GLD_LDS16(gp, lp)                                                              \
    __builtin_amdgcn_global_load_lds(                                                  \
        (const __attribute__((address_space(1))) void*)(gp),                           \
        (__attribute__((address_space(3))) void*)(lp), 16, 0, 0)

// prep: 8 rows/block (512 blocks); builds pan[p][kc][r][8] (kc<64 hi, kc>=64 lo),
// sq, per-row init, bars. (Passed R12/R13/R15.)
__global__ __launch_bounds__(256)
void prep_kernel(const float* __restrict__ e, _Float16* __restrict__ pan,
                 float* __restrict__ sq, unsigned int* __restrict__ hp,
                 unsigned int* __restrict__ hn_fall, unsigned int* __restrict__ hn_semi,
                 unsigned int* __restrict__ bars, int N, int D) {
    __shared__ float red[256];
    if (blockIdx.x == 0 && threadIdx.x < 32) bars[threadIdx.x * 32] = 0u;
    const int r0  = blockIdx.x * 8;
    const int p   = r0 >> 7;
    const int rl  = r0 & 127;
    const int r   = threadIdx.x & 7;
    const int c8  = threadIdx.x >> 3;
    const int row = r0 + r;
    const float* er = e + (size_t)row * D;
    float s = 0.f;
    #pragma unroll
    for (int it = 0; it < 2; ++it) {
        const int kw = c8 + it * 32;
        const float4 x0 = *(const float4*)&er[kw * 8];
        const float4 x1 = *(const float4*)&er[kw * 8 + 4];
        const float xv[8] = {x0.x, x0.y, x0.z, x0.w, x1.x, x1.y, x1.z, x1.w};
        half8 hi, lo;
        #pragma unroll
        for (int jj = 0; jj < 8; ++jj) {
            _Float16 h = (_Float16)xv[jj];
            hi[jj] = h;
            lo[jj] = (_Float16)(xv[jj] - (float)h);
            s += xv[jj] * xv[jj];
        }
        *(half8*)&pan[((size_t)(p * 128 + kw) * 128 + rl + r) * 8]      = hi;
        *(half8*)&pan[((size_t)(p * 128 + 64 + kw) * 128 + rl + r) * 8] = lo;
    }
    red[threadIdx.x] = s;
    __syncthreads();
    if (threadIdx.x < 8) {
        float t = 0.f;
        #pragma unroll
        for (int c = 0; c < 32; ++c) t += red[threadIdx.x + 8 * c];
        const int rw = r0 + threadIdx.x;
        sq[rw]      = t;
        hp[rw]      = 0u;           // max identity (d^2 >= 0)
        hn_fall[rw] = 0u;
        hn_semi[rw] = 0x7f800000u;  // +inf (min identity)
    }
}

// Fused: tile 256x256, 512 thr = 8 waves (2 row x 4 col) of 128x64.
// Buffer (32768 halves = 64 KB): A[kcl 0..7][256][8] | B[kcl 0..7][256][8] @16384.
// kcl 0..3 = hi k-chunks (4t..4t+3), 4..7 = lo. Double-buffered. 1 block/CU.
__global__ __launch_bounds__(512, 2)
void fused_kernel(const _Float16* __restrict__ pan, const int* __restrict__ labels,
                  const float* __restrict__ sq,
                  unsigned int* __restrict__ hp,
                  unsigned int* __restrict__ hn_fall,
                  unsigned int* __restrict__ hn_semi,
                  unsigned int* __restrict__ bars,
                  float* __restrict__ out,
                  int N, int D, unsigned int nrowblocks, unsigned int nblocks) {
    __shared__ __attribute__((aligned(16))) _Float16 S[2][32768];   // 128 KB
    __shared__ float sq_r[256], sq_c[256], hp_r[256];
    __shared__ int   lab_r[256], lab_c[256];
    __shared__ int   lastflag;

    const int tid  = threadIdx.x;
    const int lane = tid & 63;
    const int wave = tid >> 6;             // 0..7
    const int wr   = (wave >> 2) * 128;    // 0,128
    const int wcol = (wave & 3) * 64;      // 0,64,128,192
    const int mrow = lane & 31;
    const int half_id = lane >> 5;

    // XCD swizzle: each of 8 XCDs gets a 4(px) x 8(py) region of the 16x16 grid
    const int j  = blockIdx.x & 7;
    const int i  = blockIdx.x >> 3;        // 0..31
    const int px = (j & 3) * 4 + (i & 3);          // 0..15 (256-col tiles)
    const int py = (j >> 2) * 8 + (i >> 2);        // 0..15 (256-row tiles)
    const int rowBase = py * 256;
    const int colBase = px * 256;

    if (tid < 256) {
        sq_r[tid]  = sq[rowBase + tid];
        lab_r[tid] = labels[rowBase + tid];
    } else {
        const int t2 = tid - 256;
        sq_c[t2]  = sq[colBase + t2];
        lab_c[t2] = labels[colBase + t2];
    }

    floatx16 acc[2][4];   // acc[bj][ai]: cols in regs (bj), rows in lanes (ai)
    #pragma unroll
    for (int b = 0; b < 2; ++b)
        #pragma unroll
        for (int a = 0; a < 4; ++a)
            #pragma unroll
            for (int r = 0; r < 16; ++r) acc[b][a][r] = 0.f;

    // 64 slabs of 1 KB per K-tile: A = 8 kcl x 4 row-quarters, B same @ +16384.
    // wave w owns slabs 8w..8w+7.
    auto stage_slab = [&](int buf, int t, int u) {
        const int s = wave * 8 + u;
        int kcl, pp, rowin, lofs;
        if (s < 32) {                      // A slab
            kcl = s >> 2; const int rq = s & 3;
            pp    = 2 * py + (rq >> 1);
            rowin = (rq & 1) * 64 + lane;
            lofs  = (kcl * 256 + rq * 64) * 8;
        } else {                           // B slab
            const int u2 = s - 32;
            kcl = u2 >> 2; const int cq = u2 & 3;
            pp    = 2 * px + (cq >> 1);
            rowin = (cq & 1) * 64 + lane;
            lofs  = 16384 + (kcl * 256 + cq * 64) * 8;
        }
        const int kc = (kcl < 4) ? (4 * t + kcl) : (64 + 4 * t + (kcl - 4));
        const _Float16* g = pan + ((size_t)(pp * 128 + kc) * 128 + rowin) * 8;
        GLD_LDS16(g, &S[buf][lofs]);
    };

    // prologue: stage K-tile 0, full drain once (also covers meta-LDS writes).
    #pragma unroll
    for (int u = 0; u < 8; ++u) stage_slab(0, 0, u);
    __syncthreads();

    #pragma unroll 1
    for (int t = 0; t < 16; ++t) {
        const int cur = t & 1;
        const _Float16* Sc = &S[cur][0];
        // issue next tile's DMAs first: full tile to land before drain.
        if (t + 1 < 16) {
            #pragma unroll
            for (int u = 0; u < 8; ++u) stage_slab(cur ^ 1, t + 1, u);
        }
        auto mm = [&](const half8* bq, const half8* aq) {
            #pragma unroll
            for (int bj = 0; bj < 2; ++bj)
                #pragma unroll
                for (int ai = 0; ai < 4; ++ai)
                    acc[bj][ai] = __builtin_amdgcn_mfma_f32_32x32x16_f16(
                        bq[bj], aq[ai], acc[bj][ai], 0, 0, 0);
        };
        #pragma unroll
        for (int ks = 0; ks < 2; ++ks) {
            const int kb = 2 * ks;
            half8 ah[4], bh[2], al[4], bl[2];
            #pragma unroll
            for (int ai = 0; ai < 4; ++ai)
                ah[ai] = *(const half8*)&Sc[((kb + half_id) * 256 + wr + ai * 32 + mrow) * 8];
            #pragma unroll
            for (int bj = 0; bj < 2; ++bj)
                bh[bj] = *(const half8*)&Sc[16384 + ((kb + half_id) * 256 + wcol + bj * 32 + mrow) * 8];
            #pragma unroll
            for (int ai = 0; ai < 4; ++ai)
                al[ai] = *(const half8*)&Sc[((4 + kb + half_id) * 256 + wr + ai * 32 + mrow) * 8];
            #pragma unroll
            for (int bj = 0; bj < 2; ++bj)
                bl[bj] = *(const half8*)&Sc[16384 + ((4 + kb + half_id) * 256 + wcol + bj * 32 + mrow) * 8];
            __builtin_amdgcn_s_setprio(1);
            mm(bh, ah);                    // hi.hi
            mm(bh, al);                    // lo.hi
            mm(bl, ah);                    // hi.lo
            __builtin_amdgcn_s_setprio(0);
        }
        asm volatile("s_waitcnt vmcnt(0)" ::: "memory");
        __builtin_amdgcn_s_barrier();
        asm volatile("" ::: "memory");
    }

    // ---- epilogue (d^2 domain): rows in lanes. row(ai) = wr + ai*32 + mrow ----
    float sqr[4]; int labr[4];
    #pragma unroll
    for (int ai = 0; ai < 4; ++ai) {
        sqr[ai]  = sq_r[wr + ai * 32 + mrow];
        labr[ai] = lab_r[wr + ai * 32 + mrow];
    }

    // ---- phase 1: hp / hn_fall as max d^2 (sqrt deferred to final reduce) ----
    #pragma unroll
    for (int ai = 0; ai < 4; ++ai) {
        float vp = 0.f, vn = 0.f;
        #pragma unroll
        for (int bj = 0; bj < 2; ++bj) {
            #pragma unroll
            for (int r = 0; r < 16; ++r) {
                const int c = wcol + bj * 32 + (r & 3) + 8 * (r >> 2) + 4 * half_id;
                float d2 = fmaxf(sqr[ai] + sq_c[c] - 2.0f * acc[bj][ai][r], 1e-12f);
                const bool pos = (labr[ai] == lab_c[c]);
                vp = fmaxf(vp, pos ? d2 : 0.f);
                vn = fmaxf(vn, pos ? 0.f : d2);
            }
        }
        vp = fmaxf(vp, __shfl_xor(vp, 32, 64));   // merge col halves
        vn = fmaxf(vn, __shfl_xor(vn, 32, 64));
        if (half_id == 0) {
            atomicMax(&hp[rowBase + wr + ai * 32 + mrow],      __float_as_uint(vp));
            atomicMax(&hn_fall[rowBase + wr + ai * 32 + mrow], __float_as_uint(vn));
        }
    }

    // ---- per-row-panel barrier: 16 col-blocks share each py; all co-resident ----
    __syncthreads();
    unsigned int* ctr = &bars[py * 32];
    if (tid == 0) {
        __threadfence();
        atomicAdd(ctr, 1u);
        while (__hip_atomic_load(ctr, __ATOMIC_ACQUIRE, __HIP_MEMORY_SCOPE_AGENT)
               < nrowblocks)
            __builtin_amdgcn_s_sleep(32);
    }
    __syncthreads();
    if (tid < 256)
        hp_r[tid] = __uint_as_float(__hip_atomic_load(&hp[rowBase + tid],
                                    __ATOMIC_RELAXED, __HIP_MEMORY_SCOPE_AGENT));
    __syncthreads();

    // ---- phase 2: hn_semi = min{d^2 : neg, d^2 > hp^2} (sqrt monotone) ----
    #pragma unroll
    for (int ai = 0; ai < 4; ++ai) {
        const float hpv2 = hp_r[wr + ai * 32 + mrow];
        float vm = __builtin_inff();
        #pragma unroll
        for (int bj = 0; bj < 2; ++bj) {
            #pragma unroll
            for (int r = 0; r < 16; ++r) {
                const int c = wcol + bj * 32 + (r & 3) + 8 * (r >> 2) + 4 * half_id;
                float d2 = fmaxf(sqr[ai] + sq_c[c] - 2.0f * acc[bj][ai][r], 1e-12f);
                const bool cand = (labr[ai] != lab_c[c]) && (d2 > hpv2);
                vm = fminf(vm, cand ? d2 : __builtin_inff());
            }
        }
        vm = fminf(vm, __shfl_xor(vm, 32, 64));
        if (half_id == 0)
            atomicMin(&hn_semi[rowBase + wr + ai * 32 + mrow], __float_as_uint(vm));
    }

    // ---- last-block final reduction (does the deferred sqrts) ----
    __syncthreads();
    if (tid == 0) {
        __threadfence();
        unsigned int old = atomicAdd(&bars[992], 1u);
        lastflag = (old == nblocks - 1) ? 1 : 0;
    }
    __syncthreads();
    if (!lastflag) return;
    if (tid == 0) __threadfence();      // acquire before cross-XCD reads
    __syncthreads();

    float* FS = (float*)&S[0][0];       // 512 sums
    int*   IC = (int*)(FS + 512);       // 512 counts
    int*   IA = IC + 512;               // 512 any-flags
    int any = 0;
    for (int r = tid; r < N; r += 512) {
        float h  = sqrtf(__uint_as_float(__hip_atomic_load(&hp[r],      __ATOMIC_RELAXED, __HIP_MEMORY_SCOPE_AGENT)));
        float hs = sqrtf(__uint_as_float(__hip_atomic_load(&hn_semi[r], __ATOMIC_RELAXED, __HIP_MEMORY_SCOPE_AGENT)));
        any |= (hs < h + MARGIN) ? 1 : 0;
    }
    IA[tid] = any;
    __syncthreads();
    for (int s = 256; s; s >>= 1) {
        if (tid < s) IA[tid] |= IA[tid + s];
        __syncthreads();
    }
    const bool has_semi = IA[0] != 0;
    float sum = 0.f; int valid = 0;
    for (int r = tid; r < N; r += 512) {
        float h  = sqrtf(__uint_as_float(__hip_atomic_load(&hp[r], __ATOMIC_RELAXED, __HIP_MEMORY_SCOPE_AGENT)));
        float hn = has_semi
            ? sqrtf(__uint_as_float(__hip_atomic_load(&hn_semi[r], __ATOMIC_RELAXED, __HIP_MEMORY_SCOPE_AGENT)))
            : sqrtf(__uint_as_float(__hip_atomic_load(&hn_fall[r], __ATOMIC_RELAXED, __HIP_MEMORY_SCOPE_AGENT)));
        float t = fmaxf(h - hn + MARGIN, 0.f);
        if (!(t > 0.f)) t = 0.f;        // -inf guard (hn=+inf rows)
        sum += t;
        valid += (t > 0.f) ? 1 : 0;
    }
    FS[tid] = sum; IC[tid] = valid;
    __syncthreads();
    for (int s = 256; s; s >>= 1) {
        if (tid < s) { FS[tid] += FS[tid + s]; IC[tid] += IC[tid + s]; }
        __syncthreads();
    }
    if (tid == 0) {
        float total = FS[0]; int v = IC[0];
        out[0] = (v > 0) ? (total / (float)v) : (total / (float)N);
    }
}

extern "C" void kernel_launch(void* const* d_in, const int* in_sizes, int n_in,
                              void* d_out, int out_size, void* d_ws, size_t ws_size,
                              hipStream_t stream) {
    const float* e      = (const float*)d_in[0];
    const int*   labels = (const int*)d_in[1];
    const int N = in_sizes[1];
    const int D = in_sizes[0] / N;
    float* out = (float*)d_out;

    float*        sq      = (float*)d_ws;
    unsigned int* hp      = (unsigned int*)d_ws + N;
    unsigned int* hn_fall = hp + N;
    unsigned int* hn_semi = hn_fall + N;
    unsigned int* bars    = hn_semi + N;     // 32 counters (128B-spaced) + done @992

    const size_t small_bytes = ((size_t)(4 * N + 1024) * 4 + 255) & ~(size_t)255;
    _Float16* pan = (_Float16*)((char*)d_ws + small_bytes);

    prep_kernel<<<N / 8, 256, 0, stream>>>(e, pan, sq, hp, hn_fall, hn_semi, bars, N, D);

    const int ntx = N / 256, nty = N / 256;  // 16 x 16 tiles = 256 blocks = 1/CU
    fused_kernel<<<ntx * nty, 512, 0, stream>>>(pan, labels, sq, hp, hn_fall, hn_semi,
                                                bars, out, N, D,
                                                (unsigned)ntx, (unsigned)(ntx * nty));
}

// Round 12
// 127.000 us; speedup vs baseline: 1.3812x; 1.0138x over previous
//
#include <hip/hip_runtime.h>
#include <math.h>

// OnlineTripletLoss on MI355X — Round 22.
// R21 post-mortem: d^2 epilogue WON (total 137.5 -> 128.7, fused 82 -> 75.4,
//   VALUBusy 37 -> 19%). Session closure on scheduling: counted-vmcnt is null here
//   because DMAs are issued a full tile (~5 kcyc) before their drain — the slack
//   already covers L2 latency (m218's gain requires tight-slack pipelines).
// R22: address-hoist micro-opt. Per-tile stage_slab recomputed 8 branchy slab
//   addresses (~1.6 kcyc/tile VALU). The slab global addresses have a CONSTANT
//   8 KB/tile stride (kc += 4 per tile, hi and lo alike) -> precompute gptr[8] +
//   lofs[8] once (fully unrolled, static-indexed = registers), bump by 4096 halves
//   per tile. No sync/precision/layout change; R21 is the fallback.
// ws: sq[N] | hp[N] | hn_fall[N] | hn_semi[N] | bars[1024] | pad | pan[N*2D] f16

constexpr float MARGIN = 0.3f;

typedef _Float16 half8    __attribute__((ext_vector_type(8)));
typedef float    floatx16 __attribute__((ext_vector_type(16)));

#define GLD_LDS16(gp, lp)                                                              \
    __builtin_amdgcn_global_load_lds(                                                  \
        (const __attribute__((address_space(1))) void*)(gp),                           \
        (__attribute__((address_space(3))) void*)(lp), 16, 0, 0)

// prep: 8 rows/block (512 blocks); builds pan[p][kc][r][8] (kc<64 hi, kc>=64 lo),
// sq, per-row init, bars. (Passed R12/R13/R15/R21.)
__global__ __launch_bounds__(256)
void prep_kernel(const float* __restrict__ e, _Float16* __restrict__ pan,
                 float* __restrict__ sq, unsigned int* __restrict__ hp,
                 unsigned int* __restrict__ hn_fall, unsigned int* __restrict__ hn_semi,
                 unsigned int* __restrict__ bars, int N, int D) {
    __shared__ float red[256];
    if (blockIdx.x == 0 && threadIdx.x < 32) bars[threadIdx.x * 32] = 0u;
    const int r0  = blockIdx.x * 8;
    const int p   = r0 >> 7;
    const int rl  = r0 & 127;
    const int r   = threadIdx.x & 7;
    const int c8  = threadIdx.x >> 3;
    const int row = r0 + r;
    const float* er = e + (size_t)row * D;
    float s = 0.f;
    #pragma unroll
    for (int it = 0; it < 2; ++it) {
        const int kw = c8 + it * 32;
        const float4 x0 = *(const float4*)&er[kw * 8];
        const float4 x1 = *(const float4*)&er[kw * 8 + 4];
        const float xv[8] = {x0.x, x0.y, x0.z, x0.w, x1.x, x1.y, x1.z, x1.w};
        half8 hi, lo;
        #pragma unroll
        for (int jj = 0; jj < 8; ++jj) {
            _Float16 h = (_Float16)xv[jj];
            hi[jj] = h;
            lo[jj] = (_Float16)(xv[jj] - (float)h);
            s += xv[jj] * xv[jj];
        }
        *(half8*)&pan[((size_t)(p * 128 + kw) * 128 + rl + r) * 8]      = hi;
        *(half8*)&pan[((size_t)(p * 128 + 64 + kw) * 128 + rl + r) * 8] = lo;
    }
    red[threadIdx.x] = s;
    __syncthreads();
    if (threadIdx.x < 8) {
        float t = 0.f;
        #pragma unroll
        for (int c = 0; c < 32; ++c) t += red[threadIdx.x + 8 * c];
        const int rw = r0 + threadIdx.x;
        sq[rw]      = t;
        hp[rw]      = 0u;           // max identity (d^2 >= 0)
        hn_fall[rw] = 0u;
        hn_semi[rw] = 0x7f800000u;  // +inf (min identity)
    }
}

// Fused: tile 256x256, 512 thr = 8 waves (2 row x 4 col) of 128x64.
// Buffer (32768 halves = 64 KB): A[kcl 0..7][256][8] | B[kcl 0..7][256][8] @16384.
// kcl 0..3 = hi k-chunks (4t..4t+3), 4..7 = lo. Double-buffered. 1 block/CU.
__global__ __launch_bounds__(512, 2)
void fused_kernel(const _Float16* __restrict__ pan, const int* __restrict__ labels,
                  const float* __restrict__ sq,
                  unsigned int* __restrict__ hp,
                  unsigned int* __restrict__ hn_fall,
                  unsigned int* __restrict__ hn_semi,
                  unsigned int* __restrict__ bars,
                  float* __restrict__ out,
                  int N, int D, unsigned int nrowblocks, unsigned int nblocks) {
    __shared__ __attribute__((aligned(16))) _Float16 S[2][32768];   // 128 KB
    __shared__ float sq_r[256], sq_c[256], hp_r[256];
    __shared__ int   lab_r[256], lab_c[256];
    __shared__ int   lastflag;

    const int tid  = threadIdx.x;
    const int lane = tid & 63;
    const int wave = tid >> 6;             // 0..7
    const int wr   = (wave >> 2) * 128;    // 0,128
    const int wcol = (wave & 3) * 64;      // 0,64,128,192
    const int mrow = lane & 31;
    const int half_id = lane >> 5;

    // XCD swizzle: each of 8 XCDs gets a 4(px) x 8(py) region of the 16x16 grid
    const int j  = blockIdx.x & 7;
    const int i  = blockIdx.x >> 3;        // 0..31
    const int px = (j & 3) * 4 + (i & 3);          // 0..15 (256-col tiles)
    const int py = (j >> 2) * 8 + (i >> 2);        // 0..15 (256-row tiles)
    const int rowBase = py * 256;
    const int colBase = px * 256;

    if (tid < 256) {
        sq_r[tid]  = sq[rowBase + tid];
        lab_r[tid] = labels[rowBase + tid];
    } else {
        const int t2 = tid - 256;
        sq_c[t2]  = sq[colBase + t2];
        lab_c[t2] = labels[colBase + t2];
    }

    floatx16 acc[2][4];   // acc[bj][ai]: cols in regs (bj), rows in lanes (ai)
    #pragma unroll
    for (int b = 0; b < 2; ++b)
        #pragma unroll
        for (int a = 0; a < 4; ++a)
            #pragma unroll
            for (int r = 0; r < 16; ++r) acc[b][a][r] = 0.f;

    // ---- hoisted slab addressing: 8 slabs/wave, constant 4096-half (8 KB) stride
    // per K-tile (kc advances by 4 chunks/tile for both hi and lo slabs). ----
    const _Float16* gptr[8];
    int lofs_arr[8];
    #pragma unroll
    for (int u = 0; u < 8; ++u) {
        const int s = wave * 8 + u;
        int kcl, pp, rowin, lofs;
        if (s < 32) {                      // A slab: kcl = s>>2, row-quarter = s&3
            kcl = s >> 2; const int rq = s & 3;
            pp    = 2 * py + (rq >> 1);
            rowin = (rq & 1) * 64 + lane;
            lofs  = (kcl * 256 + rq * 64) * 8;
        } else {                           // B slab
            const int u2 = s - 32;
            kcl = u2 >> 2; const int cq = u2 & 3;
            pp    = 2 * px + (cq >> 1);
            rowin = (cq & 1) * 64 + lane;
            lofs  = 16384 + (kcl * 256 + cq * 64) * 8;
        }
        const int kc0 = (kcl < 4) ? kcl : (64 + kcl - 4);   // tile-0 k-chunk
        gptr[u]     = pan + ((size_t)(pp * 128 + kc0) * 128 + rowin) * 8;
        lofs_arr[u] = lofs;
    }

    // prologue: stage K-tile 0, full drain once (also covers meta-LDS writes).
    #pragma unroll
    for (int u = 0; u < 8; ++u) GLD_LDS16(gptr[u], &S[0][lofs_arr[u]]);
    #pragma unroll
    for (int u = 0; u < 8; ++u) gptr[u] += 4096;
    __syncthreads();

    #pragma unroll 1
    for (int t = 0; t < 16; ++t) {
        const int cur = t & 1;
        const _Float16* Sc = &S[cur][0];
        // issue next tile's DMAs first: full tile of slack before the drain.
        if (t + 1 < 16) {
            #pragma unroll
            for (int u = 0; u < 8; ++u) GLD_LDS16(gptr[u], &S[cur ^ 1][lofs_arr[u]]);
            #pragma unroll
            for (int u = 0; u < 8; ++u) gptr[u] += 4096;
        }
        auto mm = [&](const half8* bq, const half8* aq) {
            #pragma unroll
            for (int bj = 0; bj < 2; ++bj)
                #pragma unroll
                for (int ai = 0; ai < 4; ++ai)
                    acc[bj][ai] = __builtin_amdgcn_mfma_f32_32x32x16_f16(
                        bq[bj], aq[ai], acc[bj][ai], 0, 0, 0);
        };
        #pragma unroll
        for (int ks = 0; ks < 2; ++ks) {
            const int kb = 2 * ks;
            half8 ah[4], bh[2], al[4], bl[2];
            #pragma unroll
            for (int ai = 0; ai < 4; ++ai)
                ah[ai] = *(const half8*)&Sc[((kb + half_id) * 256 + wr + ai * 32 + mrow) * 8];
            #pragma unroll
            for (int bj = 0; bj < 2; ++bj)
                bh[bj] = *(const half8*)&Sc[16384 + ((kb + half_id) * 256 + wcol + bj * 32 + mrow) * 8];
            #pragma unroll
            for (int ai = 0; ai < 4; ++ai)
                al[ai] = *(const half8*)&Sc[((4 + kb + half_id) * 256 + wr + ai * 32 + mrow) * 8];
            #pragma unroll
            for (int bj = 0; bj < 2; ++bj)
                bl[bj] = *(const half8*)&Sc[16384 + ((4 + kb + half_id) * 256 + wcol + bj * 32 + mrow) * 8];
            __builtin_amdgcn_s_setprio(1);
            mm(bh, ah);                    // hi.hi
            mm(bh, al);                    // lo.hi
            mm(bl, ah);                    // hi.lo
            __builtin_amdgcn_s_setprio(0);
        }
        asm volatile("s_waitcnt vmcnt(0)" ::: "memory");
        __builtin_amdgcn_s_barrier();
        asm volatile("" ::: "memory");
    }

    // ---- epilogue (d^2 domain): rows in lanes. row(ai) = wr + ai*32 + mrow ----
    float sqr[4]; int labr[4];
    #pragma unroll
    for (int ai = 0; ai < 4; ++ai) {
        sqr[ai]  = sq_r[wr + ai * 32 + mrow];
        labr[ai] = lab_r[wr + ai * 32 + mrow];
    }

    // ---- phase 1: hp / hn_fall as max d^2 (sqrt deferred to final reduce) ----
    #pragma unroll
    for (int ai = 0; ai < 4; ++ai) {
        float vp = 0.f, vn = 0.f;
        #pragma unroll
        for (int bj = 0; bj < 2; ++bj) {
            #pragma unroll
            for (int r = 0; r < 16; ++r) {
                const int c = wcol + bj * 32 + (r & 3) + 8 * (r >> 2) + 4 * half_id;
                float d2 = fmaxf(sqr[ai] + sq_c[c] - 2.0f * acc[bj][ai][r], 1e-12f);
                const bool pos = (labr[ai] == lab_c[c]);
                vp = fmaxf(vp, pos ? d2 : 0.f);
                vn = fmaxf(vn, pos ? 0.f : d2);
            }
        }
        vp = fmaxf(vp, __shfl_xor(vp, 32, 64));   // merge col halves
        vn = fmaxf(vn, __shfl_xor(vn, 32, 64));
        if (half_id == 0) {
            atomicMax(&hp[rowBase + wr + ai * 32 + mrow],      __float_as_uint(vp));
            atomicMax(&hn_fall[rowBase + wr + ai * 32 + mrow], __float_as_uint(vn));
        }
    }

    // ---- per-row-panel barrier: 16 col-blocks share each py; all co-resident ----
    __syncthreads();
    unsigned int* ctr = &bars[py * 32];
    if (tid == 0) {
        __threadfence();
        atomicAdd(ctr, 1u);
        while (__hip_atomic_load(ctr, __ATOMIC_ACQUIRE, __HIP_MEMORY_SCOPE_AGENT)
               < nrowblocks)
            __builtin_amdgcn_s_sleep(32);
    }
    __syncthreads();
    if (tid < 256)
        hp_r[tid] = __uint_as_float(__hip_atomic_load(&hp[rowBase + tid],
                                    __ATOMIC_RELAXED, __HIP_MEMORY_SCOPE_AGENT));
    __syncthreads();

    // ---- phase 2: hn_semi = min{d^2 : neg, d^2 > hp^2} (sqrt monotone) ----
    #pragma unroll
    for (int ai = 0; ai < 4; ++ai) {
        const float hpv2 = hp_r[wr + ai * 32 + mrow];
        float vm = __builtin_inff();
        #pragma unroll
        for (int bj = 0; bj < 2; ++bj) {
            #pragma unroll
            for (int r = 0; r < 16; ++r) {
                const int c = wcol + bj * 32 + (r & 3) + 8 * (r >> 2) + 4 * half_id;
                float d2 = fmaxf(sqr[ai] + sq_c[c] - 2.0f * acc[bj][ai][r], 1e-12f);
                const bool cand = (labr[ai] != lab_c[c]) && (d2 > hpv2);
                vm = fminf(vm, cand ? d2 : __builtin_inff());
            }
        }
        vm = fminf(vm, __shfl_xor(vm, 32, 64));
        if (half_id == 0)
            atomicMin(&hn_semi[rowBase + wr + ai * 32 + mrow], __float_as_uint(vm));
    }

    // ---- last-block final reduction (does the deferred sqrts) ----
    __syncthreads();
    if (tid == 0) {
        __threadfence();
        unsigned int old = atomicAdd(&bars[992], 1u);
        lastflag = (old == nblocks - 1) ? 1 : 0;
    }
    __syncthreads();
    if (!lastflag) return;
    if (tid == 0) __threadfence();      // acquire before cross-XCD reads
    __syncthreads();

    float* FS = (float*)&S[0][0];       // 512 sums
    int*   IC = (int*)(FS + 512);       // 512 counts
    int*   IA = IC + 512;               // 512 any-flags
    int any = 0;
    for (int r = tid; r < N; r += 512) {
        float h  = sqrtf(__uint_as_float(__hip_atomic_load(&hp[r],      __ATOMIC_RELAXED, __HIP_MEMORY_SCOPE_AGENT)));
        float hs = sqrtf(__uint_as_float(__hip_atomic_load(&hn_semi[r], __ATOMIC_RELAXED, __HIP_MEMORY_SCOPE_AGENT)));
        any |= (hs < h + MARGIN) ? 1 : 0;
    }
    IA[tid] = any;
    __syncthreads();
    for (int s = 256; s; s >>= 1) {
        if (tid < s) IA[tid] |= IA[tid + s];
        __syncthreads();
    }
    const bool has_semi = IA[0] != 0;
    float sum = 0.f; int valid = 0;
    for (int r = tid; r < N; r += 512) {
        float h  = sqrtf(__uint_as_float(__hip_atomic_load(&hp[r], __ATOMIC_RELAXED, __HIP_MEMORY_SCOPE_AGENT)));
        float hn = has_semi
            ? sqrtf(__uint_as_float(__hip_atomic_load(&hn_semi[r], __ATOMIC_RELAXED, __HIP_MEMORY_SCOPE_AGENT)))
            : sqrtf(__uint_as_float(__hip_atomic_load(&hn_fall[r], __ATOMIC_RELAXED, __HIP_MEMORY_SCOPE_AGENT)));
        float t = fmaxf(h - hn + MARGIN, 0.f);
        if (!(t > 0.f)) t = 0.f;        // -inf guard (hn=+inf rows)
        sum += t;
        valid += (t > 0.f) ? 1 : 0;
    }
    FS[tid] = sum; IC[tid] = valid;
    __syncthreads();
    for (int s = 256; s; s >>= 1) {
        if (tid < s) { FS[tid] += FS[tid + s]; IC[tid] += IC[tid + s]; }
        __syncthreads();
    }
    if (tid == 0) {
        float total = FS[0]; int v = IC[0];
        out[0] = (v > 0) ? (total / (float)v) : (total / (float)N);
    }
}

extern "C" void kernel_launch(void* const* d_in, const int* in_sizes, int n_in,
                              void* d_out, int out_size, void* d_ws, size_t ws_size,
                              hipStream_t stream) {
    const float* e      = (const float*)d_in[0];
    const int*   labels = (const int*)d_in[1];
    const int N = in_sizes[1];
    const int D = in_sizes[0] / N;
    float* out = (float*)d_out;

    float*        sq      = (float*)d_ws;
    unsigned int* hp      = (unsigned int*)d_ws + N;
    unsigned int* hn_fall = hp + N;
    unsigned int* hn_semi = hn_fall + N;
    unsigned int* bars    = hn_semi + N;     // 32 counters (128B-spaced) + done @992

    const size_t small_bytes = ((size_t)(4 * N + 1024) * 4 + 255) & ~(size_t)255;
    _Float16* pan = (_Float16*)((char*)d_ws + small_bytes);

    prep_kernel<<<N / 8, 256, 0, stream>>>(e, pan, sq, hp, hn_fall, hn_semi, bars, N, D);

    const int ntx = N / 256, nty = N / 256;  // 16 x 16 tiles = 256 blocks = 1/CU
    fused_kernel<<<ntx * nty, 512, 0, stream>>>(pan, labels, sq, hp, hn_fall, hn_semi,
                                                bars, out, N, D,
                                                (unsigned)ntx, (unsigned)(ntx * nty));
}